// Round 2
// baseline (1323.617 us; speedup 1.0000x reference)
//
#include <hip/hip_runtime.h>
#include <hip/hip_bf16.h>
#include <stdint.h>

// ---------- constants ----------
#define BATCH 64
#define CC 384
#define NHEAD 12
#define KD 32
#define NTOK 49
#define LL 784
#define MTOT 50176        // BATCH*LL = 1024 windows * 49
#define HID 1536
#define QKV_OUT 1152
#define SCALE 0.17677669529663687f
#define EPS 1e-5f

typedef __bf16 bf16x8 __attribute__((ext_vector_type(8)));
typedef float f32x4 __attribute__((ext_vector_type(4)));

__device__ __forceinline__ float bf2f(unsigned short u) {
  union { unsigned int u; float f; } cv; cv.u = ((unsigned int)u) << 16; return cv.f;
}
__device__ __forceinline__ unsigned short f2bf(float f) {
  union { float f; unsigned int u; } cv; cv.f = f;
  unsigned int r = cv.u + 0x7FFFu + ((cv.u >> 16) & 1u);
  return (unsigned short)(r >> 16);
}

// ---------- dtype detection ----------
// Genuine bf16 N(0,1) data never has exponent 0xFF. fp32 data read as u16
// pairs: low halves are uniform mantissa bits -> ~1/256 have exp==0xFF.
__global__ void detect_kernel(const unsigned short* __restrict__ x, int* flag) {
  __shared__ int cnt;
  if (threadIdx.x == 0) cnt = 0;
  __syncthreads();
  int c = 0;
  for (int i = threadIdx.x; i < 4096; i += 256) {
    if (((x[i] >> 7) & 0xFF) == 0xFF) c++;
  }
  atomicAdd(&cnt, c);
  __syncthreads();
  if (threadIdx.x == 0) *flag = (cnt > 0) ? 1 : 0;
}

// ---------- input canonicalization: everything -> internal bf16 ----------
struct CvtArgs {
  const void* src[19];
  unsigned int n[19];
  unsigned int off[19];
};
__global__ __launch_bounds__(256) void convert_kernel(
    CvtArgs a, unsigned short* __restrict__ dst, const int* __restrict__ flag) {
  const int which = blockIdx.y;
  const unsigned int nn = a.n[which];
  unsigned short* d = dst + a.off[which];
  const unsigned int stride = gridDim.x * blockDim.x;
  unsigned int i = blockIdx.x * blockDim.x + threadIdx.x;
  if (*flag) {
    const float* s = (const float*)a.src[which];
    for (; i < nn; i += stride) d[i] = f2bf(s[i]);
  } else {
    const unsigned short* s = (const unsigned short*)a.src[which];
    for (; i < nn; i += stride) d[i] = s[i];
  }
}

// ---------- LayerNorm (+ optional window gather) ----------
template <bool WINDOW>
__global__ __launch_bounds__(128) void ln_kernel(
    const unsigned short* __restrict__ x, const unsigned short* __restrict__ g,
    const unsigned short* __restrict__ b, unsigned short* __restrict__ out) {
  const int tid = threadIdx.x;
  size_t src_row, dst_row;
  if (WINDOW) {
    int wi = blockIdx.y, n = blockIdx.x;
    int bb = wi >> 4, wb = wi & 15;
    int nh_i = wb >> 2, nw_i = wb & 3;
    int hs = n / 7, wsx = n - hs * 7;
    int l = nh_i * 196 + hs * 28 + nw_i * 7 + wsx;
    src_row = (size_t)bb * LL + l;
    dst_row = (size_t)wi * NTOK + n;
  } else {
    src_row = dst_row = (size_t)blockIdx.y * 49 + blockIdx.x;
  }
  const unsigned short* xr = x + src_row * CC;
  float vals[3]; float s = 0.f, sq = 0.f;
  for (int j = 0; j < 3; ++j) {
    vals[j] = bf2f(xr[tid + 128 * j]);
    s += vals[j]; sq += vals[j] * vals[j];
  }
  for (int off = 32; off; off >>= 1) { s += __shfl_xor(s, off); sq += __shfl_xor(sq, off); }
  __shared__ float red[4];
  const int wv = tid >> 6;
  if ((tid & 63) == 0) { red[wv] = s; red[2 + wv] = sq; }
  __syncthreads();
  float tot = red[0] + red[1], totq = red[2] + red[3];
  float mean = tot * (1.f / CC);
  float var = totq * (1.f / CC) - mean * mean;
  float inv = rsqrtf(var + EPS);
  unsigned short* orow = out + dst_row * CC;
  for (int j = 0; j < 3; ++j) {
    int c = tid + 128 * j;
    float y = (vals[j] - mean) * inv * bf2f(g[c]) + bf2f(b[c]);
    orow[c] = f2bf(y);
  }
}

// ---------- GEMM: out[M,N] = A[M,K] @ W[N,K]^T + bias, with epilogues ----------
enum { EP_PLAIN = 0, EP_GELU = 1, EP_WINRES = 2, EP_RES2 = 3 };

template <int EP>
__global__ __launch_bounds__(256) void gemm_bt(
    const unsigned short* __restrict__ A, const unsigned short* __restrict__ W,
    const unsigned short* __restrict__ bias, const unsigned short* __restrict__ res,
    void* __restrict__ outp, int K, int N, int m_off, const int* __restrict__ flagp) {
  __shared__ unsigned short Al[64][40];
  __shared__ unsigned short Bl[64][40];
  const int tid = threadIdx.x;
  const int lane = tid & 63;
  const int wave = tid >> 6;
  const int bm = blockIdx.x * 64;
  const int bn = blockIdx.y * 64;
  const int wm = (wave >> 1) * 32;
  const int wn = (wave & 1) * 32;
  const int rowL = tid >> 2;
  const int colL = (tid & 3) * 8;
  const unsigned short* Ap = A + (size_t)(bm + rowL) * K + colL;
  const unsigned short* Wp = W + (size_t)(bn + rowL) * K + colL;
  f32x4 acc[2][2] = {};
  const int kq = (lane >> 4) * 8;
  const int fr = lane & 15;
  for (int k0 = 0; k0 < K; k0 += 32) {
    __syncthreads();
    *(uint4*)(&Al[rowL][colL]) = *(const uint4*)Ap;
    *(uint4*)(&Bl[rowL][colL]) = *(const uint4*)Wp;
    Ap += 32; Wp += 32;
    __syncthreads();
    bf16x8 a0 = *reinterpret_cast<const bf16x8*>(&Al[wm + fr][kq]);
    bf16x8 a1 = *reinterpret_cast<const bf16x8*>(&Al[wm + 16 + fr][kq]);
    bf16x8 b0 = *reinterpret_cast<const bf16x8*>(&Bl[wn + fr][kq]);
    bf16x8 b1 = *reinterpret_cast<const bf16x8*>(&Bl[wn + 16 + fr][kq]);
    acc[0][0] = __builtin_amdgcn_mfma_f32_16x16x32_bf16(a0, b0, acc[0][0], 0, 0, 0);
    acc[0][1] = __builtin_amdgcn_mfma_f32_16x16x32_bf16(a0, b1, acc[0][1], 0, 0, 0);
    acc[1][0] = __builtin_amdgcn_mfma_f32_16x16x32_bf16(a1, b0, acc[1][0], 0, 0, 0);
    acc[1][1] = __builtin_amdgcn_mfma_f32_16x16x32_bf16(a1, b1, acc[1][1], 0, 0, 0);
  }
  int isf32 = 0;
  if (EP == EP_RES2) isf32 = *flagp;
  const int qr = (lane >> 4) * 4;  // C/D: row = quad*4 + reg, col = lane&15
  for (int tm = 0; tm < 2; ++tm) {
    for (int tn = 0; tn < 2; ++tn) {
      const int n = bn + wn + tn * 16 + fr;
      const float bv = bf2f(bias[n]);
      const int mbase = bm + wm + tm * 16 + qr;
      for (int r = 0; r < 4; ++r) {
        const int mr = mbase + r;
        float v = acc[tm][tn][r] + bv;
        if (EP == EP_GELU) {
          v = 0.5f * v * (1.0f + erff(v * 0.70710678118654752f));
          ((unsigned short*)outp)[(size_t)mr * N + n] = f2bf(v);
        } else if (EP == EP_WINRES) {
          int wi = mr / 49; int nt = mr - wi * 49;
          int bb = wi >> 4; int wb = wi & 15;
          int nh_i = wb >> 2; int nw_i = wb & 3;
          int hs = nt / 7; int wsx = nt - hs * 7;
          int l = nh_i * 196 + hs * 28 + nw_i * 7 + wsx;
          size_t idx = ((size_t)bb * LL + l) * CC + n;
          v += bf2f(res[idx]);
          ((unsigned short*)outp)[idx] = f2bf(v);
        } else if (EP == EP_RES2) {
          size_t idx = (size_t)(mr + m_off) * N + n;
          v += bf2f(res[idx]);
          if (isf32) ((float*)outp)[idx] = v;
          else       ((unsigned short*)outp)[idx] = f2bf(v);
        } else {
          ((unsigned short*)outp)[(size_t)mr * N + n] = f2bf(v);
        }
      }
    }
  }
}

// ---------- windowed attention: one block per (window, head) ----------
__global__ __launch_bounds__(256) void attn_kernel(
    const unsigned short* __restrict__ qkv, const unsigned short* __restrict__ attn_bias,
    const int* __restrict__ bias_idxs, unsigned short* __restrict__ o, int wi_off) {
  __shared__ float q[NTOK][KD], k[NTOK][KD], v[NTOK][KD];
  __shared__ float S[NTOK][52];
  __shared__ float bia[NTOK];
  const int wi = blockIdx.x, h = blockIdx.y;   // wi is LOCAL (chunked) window idx
  const int tid = threadIdx.x;
  const size_t base = (size_t)wi * NTOK * QKV_OUT + h * 96;
  for (int i = tid; i < NTOK * KD; i += 256) {
    int n = i >> 5, d = i & 31;
    const unsigned short* p = qkv + base + (size_t)n * QKV_OUT + d;
    q[n][d] = bf2f(p[0]) * SCALE;
    k[n][d] = bf2f(p[32]);
    v[n][d] = bf2f(p[64]);
  }
  if (tid < NTOK) bia[tid] = bf2f(attn_bias[h * NTOK + tid]);
  __syncthreads();
  for (int i = tid; i < NTOK * NTOK; i += 256) {
    int n = i / 49, m = i - n * 49;
    float s = 0.f;
    #pragma unroll
    for (int d = 0; d < KD; ++d) s += q[n][d] * k[m][d];
    S[n][m] = s + bia[bias_idxs[i]];
  }
  __syncthreads();
  const int lane = tid & 63, wv = tid >> 6;
  for (int n = wv; n < NTOK; n += 4) {
    float val = (lane < NTOK) ? S[n][lane] : -1e30f;
    for (int off = 32; off; off >>= 1) val = fmaxf(val, __shfl_xor(val, off));
    float e = (lane < NTOK) ? expf(S[n][lane] - val) : 0.f;
    float sum = e;
    for (int off = 32; off; off >>= 1) sum += __shfl_xor(sum, off);
    if (lane < NTOK) S[n][lane] = e / sum;
  }
  __syncthreads();
  for (int i = tid; i < NTOK * KD; i += 256) {
    int n = i >> 5, d = i & 31;
    float acc = 0.f;
    #pragma unroll 7
    for (int m = 0; m < NTOK; ++m) acc += S[n][m] * v[m][d];
    o[((size_t)(wi_off + wi) * NTOK + n) * CC + h * KD + d] = f2bf(acc);
  }
}

// ---------- depthwise 3x3 conv + BN ----------
__global__ __launch_bounds__(384) void conv_bn_kernel(
    const unsigned short* __restrict__ x1, const unsigned short* __restrict__ cw,
    const unsigned short* __restrict__ bg, const unsigned short* __restrict__ bb,
    const unsigned short* __restrict__ bm, const unsigned short* __restrict__ bv,
    unsigned short* __restrict__ x2) {
  const int hw = blockIdx.x;
  const int b = blockIdx.y;
  const int c = threadIdx.x;
  const int h = hw / 28, w = hw - h * 28;
  float wt[9];
  #pragma unroll
  for (int t = 0; t < 9; ++t) wt[t] = bf2f(cw[c * 9 + t]);
  float acc = 0.f;
  #pragma unroll
  for (int dh = -1; dh <= 1; ++dh) {
    int hh = h + dh;
    if (hh < 0 || hh >= 28) continue;
    #pragma unroll
    for (int dw = -1; dw <= 1; ++dw) {
      int ww = w + dw;
      if (ww < 0 || ww >= 28) continue;
      acc += bf2f(x1[((size_t)b * LL + hh * 28 + ww) * CC + c]) * wt[(dh + 1) * 3 + (dw + 1)];
    }
  }
  float inv = rsqrtf(bf2f(bv[c]) + EPS);
  float y = (acc - bf2f(bm[c])) * (bf2f(bg[c]) * inv) + bf2f(bb[c]);
  x2[((size_t)b * LL + hw) * CC + c] = f2bf(y);
}

// ---------- launch ----------
extern "C" void kernel_launch(void* const* d_in, const int* in_sizes, int n_in,
                              void* d_out, int out_size, void* d_ws, size_t ws_size,
                              hipStream_t stream) {
  // flag at ws[0]; converted-input region starts at elem 32
  int* flag = (int*)d_ws;
  unsigned short* base = (unsigned short*)d_ws;

  CvtArgs args;
  size_t cur = 32;
  size_t off[19];
  for (int i = 0; i < 19; ++i) {
    off[i] = cur;
    args.src[i] = d_in[i];
    args.n[i] = (unsigned int)in_sizes[i];
    args.off[i] = (unsigned int)cur;
    cur += ((size_t)in_sizes[i] + 63) & ~(size_t)63;
  }
  const unsigned short* cx   = base + off[0];
  const unsigned short* cgA  = base + off[1];
  const unsigned short* cbA  = base + off[2];
  const unsigned short* cQw  = base + off[3];
  const unsigned short* cQb  = base + off[4];
  const unsigned short* cAb  = base + off[5];
  const unsigned short* cPw  = base + off[6];
  const unsigned short* cPb  = base + off[7];
  const unsigned short* cCw  = base + off[8];
  const unsigned short* cBg  = base + off[9];
  const unsigned short* cBb  = base + off[10];
  const unsigned short* cBm  = base + off[11];
  const unsigned short* cBv  = base + off[12];
  const unsigned short* cMg  = base + off[13];
  const unsigned short* cMb  = base + off[14];
  const unsigned short* cF1w = base + off[15];
  const unsigned short* cF1b = base + off[16];
  const unsigned short* cF2w = base + off[17];
  const unsigned short* cF2b = base + off[18];
  const int* bias_idxs = (const int*)d_in[19];

  // working buffers (internal bf16), region-reused:
  const size_t SZ = (size_t)MTOT * CC;     // 19267584 elems
  unsigned short* o_buf = base + cur;       // o, later ln_m output (xm)
  unsigned short* x2    = o_buf + SZ;       // conv+bn output (phase C+)
  unsigned short* qkvh  = o_buf + SZ;       // qkv half-buffer (phase A, same region)
  unsigned short* hq    = o_buf + 2 * SZ;   // fc1 quarter-buffer
  // peak = cur + 3*SZ elems * 2B  (~151 MB)

  unsigned short* xn = (unsigned short*)d_out;  // d_out doubles as xn / x1 scratch

  // 0. dtype detect + canonicalize all float inputs to bf16
  detect_kernel<<<1, 256, 0, stream>>>((const unsigned short*)d_in[0], flag);
  convert_kernel<<<dim3(1176, 19), 256, 0, stream>>>(args, base, flag);

  // 1. window partition + LN_a  -> xn (in d_out)
  ln_kernel<true><<<dim3(49, 1024), 128, 0, stream>>>(cx, cgA, cbA, xn);

  // 2+3. qkv projection + attention, chunked over 2 window-halves
  for (int half = 0; half < 2; ++half) {
    gemm_bt<EP_PLAIN><<<dim3(392, 18), 256, 0, stream>>>(
        xn + (size_t)half * 25088 * CC, cQw, cQb, nullptr, qkvh, CC, QKV_OUT, 0, nullptr);
    attn_kernel<<<dim3(512, NHEAD), 256, 0, stream>>>(qkvh, cAb, bias_idxs, o_buf, half * 512);
  }

  // 4. proj + un-window + residual(x) -> x1 (d_out, bf16)
  gemm_bt<EP_WINRES><<<dim3(784, 6), 256, 0, stream>>>(
      o_buf, cPw, cPb, cx, d_out, CC, CC, 0, nullptr);

  // 5. depthwise conv + BN -> x2
  conv_bn_kernel<<<dim3(784, BATCH), 384, 0, stream>>>(
      (const unsigned short*)d_out, cCw, cBg, cBb, cBm, cBv, x2);

  // 6. LN_m -> xm (reuse o_buf)
  ln_kernel<false><<<dim3(49, 1024), 128, 0, stream>>>(x2, cMg, cMb, o_buf);

  // 7+8. MLP chunked over 4 M-quarters; fc2 writes final output (bf16 or f32 per flag)
  for (int q4 = 0; q4 < 4; ++q4) {
    gemm_bt<EP_GELU><<<dim3(196, 24), 256, 0, stream>>>(
        o_buf + (size_t)q4 * 12544 * CC, cF1w, cF1b, nullptr, hq, CC, HID, 0, nullptr);
    gemm_bt<EP_RES2><<<dim3(196, 6), 256, 0, stream>>>(
        hq, cF2w, cF2b, x2, d_out, HID, CC, q4 * 12544, flag);
  }
}

// Round 3
// 1130.374 us; speedup vs baseline: 1.1710x; 1.1710x over previous
//
#include <hip/hip_runtime.h>
#include <hip/hip_bf16.h>
#include <stdint.h>

// ---------- constants ----------
#define BATCH 64
#define CC 384
#define NHEAD 12
#define KD 32
#define NTOK 49
#define LL 784
#define MTOT 50176        // BATCH*LL = 1024 windows * 49
#define HID 1536
#define QKV_OUT 1152
#define SCALE 0.17677669529663687f
#define EPS 1e-5f

typedef __bf16 bf16x8 __attribute__((ext_vector_type(8)));
typedef float f32x4 __attribute__((ext_vector_type(4)));

__device__ __forceinline__ float bf2f(unsigned short u) {
  union { unsigned int u; float f; } cv; cv.u = ((unsigned int)u) << 16; return cv.f;
}
__device__ __forceinline__ unsigned short f2bf(float f) {
  union { float f; unsigned int u; } cv; cv.f = f;
  unsigned int r = cv.u + 0x7FFFu + ((cv.u >> 16) & 1u);
  return (unsigned short)(r >> 16);
}
// async global->LDS, 16B per lane. LDS dest must be lane-contiguous (base+lane*16).
__device__ __forceinline__ void gl_lds16(const unsigned short* g, unsigned short* l) {
  __builtin_amdgcn_global_load_lds(
      (const __attribute__((address_space(1))) unsigned int*)g,
      (__attribute__((address_space(3))) unsigned int*)l, 16, 0, 0);
}

// ---------- dtype detection (bf16 vs fp32 wire format) ----------
__global__ void detect_kernel(const unsigned short* __restrict__ x, int* flag) {
  __shared__ int cnt;
  if (threadIdx.x == 0) cnt = 0;
  __syncthreads();
  int c = 0;
  for (int i = threadIdx.x; i < 4096; i += 256) {
    if (((x[i] >> 7) & 0xFF) == 0xFF) c++;
  }
  atomicAdd(&cnt, c);
  __syncthreads();
  if (threadIdx.x == 0) *flag = (cnt > 0) ? 1 : 0;
}

// ---------- input canonicalization: everything -> internal bf16 ----------
struct CvtArgs {
  const void* src[19];
  unsigned int n[19];
  unsigned int off[19];
};
__global__ __launch_bounds__(256) void convert_kernel(
    CvtArgs a, unsigned short* __restrict__ dst, const int* __restrict__ flag) {
  const int which = blockIdx.y;
  const unsigned int nn = a.n[which];
  unsigned short* d = dst + a.off[which];
  const unsigned int stride = gridDim.x * blockDim.x;
  unsigned int i = blockIdx.x * blockDim.x + threadIdx.x;
  if (*flag) {
    const float* s = (const float*)a.src[which];
    for (; i < nn; i += stride) d[i] = f2bf(s[i]);
  } else {
    const unsigned short* s = (const unsigned short*)a.src[which];
    for (; i < nn; i += stride) d[i] = s[i];
  }
}

// ---------- LayerNorm (+ optional window gather) ----------
template <bool WINDOW>
__global__ __launch_bounds__(128) void ln_kernel(
    const unsigned short* __restrict__ x, const unsigned short* __restrict__ g,
    const unsigned short* __restrict__ b, unsigned short* __restrict__ out) {
  const int tid = threadIdx.x;
  size_t src_row, dst_row;
  if (WINDOW) {
    int wi = blockIdx.y, n = blockIdx.x;
    int bb = wi >> 4, wb = wi & 15;
    int nh_i = wb >> 2, nw_i = wb & 3;
    int hs = n / 7, wsx = n - hs * 7;
    int l = nh_i * 196 + hs * 28 + nw_i * 7 + wsx;
    src_row = (size_t)bb * LL + l;
    dst_row = (size_t)wi * NTOK + n;
  } else {
    src_row = dst_row = (size_t)blockIdx.y * 49 + blockIdx.x;
  }
  const unsigned short* xr = x + src_row * CC;
  float vals[3]; float s = 0.f, sq = 0.f;
  for (int j = 0; j < 3; ++j) {
    vals[j] = bf2f(xr[tid + 128 * j]);
    s += vals[j]; sq += vals[j] * vals[j];
  }
  for (int off = 32; off; off >>= 1) { s += __shfl_xor(s, off); sq += __shfl_xor(sq, off); }
  __shared__ float red[4];
  const int wv = tid >> 6;
  if ((tid & 63) == 0) { red[wv] = s; red[2 + wv] = sq; }
  __syncthreads();
  float tot = red[0] + red[1], totq = red[2] + red[3];
  float mean = tot * (1.f / CC);
  float var = totq * (1.f / CC) - mean * mean;
  float inv = rsqrtf(var + EPS);
  unsigned short* orow = out + dst_row * CC;
  for (int j = 0; j < 3; ++j) {
    int c = tid + 128 * j;
    float y = (vals[j] - mean) * inv * bf2f(g[c]) + bf2f(b[c]);
    orow[c] = f2bf(y);
  }
}

// ---------- GEMM (m97 recipe): 128x128 tile, 4 waves, 4x4 acc, async LDS ----------
// out[M,N] = A[M,K] @ W[N,K]^T + bias, with epilogues
enum { EP_PLAIN = 0, EP_GELU = 1, EP_WINRES = 2, EP_RES2 = 3 };

template <int EP>
__global__ __launch_bounds__(256) void gemm128(
    const unsigned short* __restrict__ A, const unsigned short* __restrict__ W,
    const unsigned short* __restrict__ bias, const unsigned short* __restrict__ res,
    void* __restrict__ outp, int K, int N, int m_off, const int* __restrict__ flagp) {
  __shared__ __align__(16) unsigned short Al[128 * 32];
  __shared__ __align__(16) unsigned short Bl[128 * 32];
  const int tid = threadIdx.x;
  const int lane = tid & 63;
  const int wave = tid >> 6;
  const int bm = blockIdx.x * 128;
  const int bn = blockIdx.y * 128;
  const int wm = (wave >> 1) * 64;
  const int wn = (wave & 1) * 64;
  // staging: thread tid covers row tid/4 (and +64), col (tid&3)*8; lds off = tid*8 elems
  const int srow = tid >> 2;
  const int scol = (tid & 3) * 8;
  const unsigned short* Ap = A + (size_t)(bm + srow) * K + scol;
  const unsigned short* Wp = W + (size_t)(bn + srow) * K + scol;
  unsigned short* Alp = Al + tid * 8;
  unsigned short* Blp = Bl + tid * 8;
  const size_t rstep = (size_t)64 * K;
  f32x4 acc[4][4] = {};
  const int kq = (lane >> 4) * 8;
  const int fr = lane & 15;
  for (int k0 = 0; k0 < K; k0 += 32) {
    __syncthreads();
    gl_lds16(Ap, Alp);
    gl_lds16(Ap + rstep, Alp + 2048);
    gl_lds16(Wp, Blp);
    gl_lds16(Wp + rstep, Blp + 2048);
    Ap += 32; Wp += 32;
    __syncthreads();
    bf16x8 af[4], bfr[4];
    #pragma unroll
    for (int i = 0; i < 4; ++i) {
      af[i]  = *(const bf16x8*)(Al + (wm + i * 16 + fr) * 32 + kq);
      bfr[i] = *(const bf16x8*)(Bl + (wn + i * 16 + fr) * 32 + kq);
    }
    #pragma unroll
    for (int i = 0; i < 4; ++i)
      #pragma unroll
      for (int j = 0; j < 4; ++j)
        acc[i][j] = __builtin_amdgcn_mfma_f32_16x16x32_bf16(af[i], bfr[j], acc[i][j], 0, 0, 0);
  }
  int isf32 = 0;
  if (EP == EP_RES2) isf32 = *flagp;
  const int qr = (lane >> 4) * 4;  // C/D: row = quad*4 + reg, col = lane&15
  #pragma unroll
  for (int ti = 0; ti < 4; ++ti) {
    #pragma unroll
    for (int tj = 0; tj < 4; ++tj) {
      const int n = bn + wn + tj * 16 + fr;
      const float bv = bf2f(bias[n]);
      const int mbase = bm + wm + ti * 16 + qr;
      #pragma unroll
      for (int r = 0; r < 4; ++r) {
        const int mr = mbase + r;
        float v = acc[ti][tj][r] + bv;
        if (EP == EP_GELU) {
          v = 0.5f * v * (1.0f + erff(v * 0.70710678118654752f));
          ((unsigned short*)outp)[(size_t)mr * N + n] = f2bf(v);
        } else if (EP == EP_WINRES) {
          int wi = mr / 49; int nt = mr - wi * 49;
          int bb = wi >> 4; int wb = wi & 15;
          int nh_i = wb >> 2; int nw_i = wb & 3;
          int hs = nt / 7; int wsx = nt - hs * 7;
          int l = nh_i * 196 + hs * 28 + nw_i * 7 + wsx;
          size_t idx = ((size_t)bb * LL + l) * CC + n;
          v += bf2f(res[idx]);
          ((unsigned short*)outp)[idx] = f2bf(v);
        } else if (EP == EP_RES2) {
          size_t idx = (size_t)(mr + m_off) * N + n;
          v += bf2f(res[idx]);
          if (isf32) ((float*)outp)[idx] = v;
          else       ((unsigned short*)outp)[idx] = f2bf(v);
        } else {
          ((unsigned short*)outp)[(size_t)mr * N + n] = f2bf(v);
        }
      }
    }
  }
}

// ---------- windowed attention: one block per (window, head) ----------
// LDS padded to stride 33: bank = (m + d) % 32 -> conflict-free (was stride 32: all
// lanes on bank d, 5.3e7 conflicts, 228 us/dispatch).
__global__ __launch_bounds__(256) void attn_kernel(
    const unsigned short* __restrict__ qkv, const unsigned short* __restrict__ attn_bias,
    const int* __restrict__ bias_idxs, unsigned short* __restrict__ o, int wi_off) {
  __shared__ float q[NTOK][33], k[NTOK][33], v[NTOK][33];
  __shared__ float S[NTOK][52];
  __shared__ float bia[NTOK];
  const int wi = blockIdx.x, h = blockIdx.y;
  const int tid = threadIdx.x;
  const size_t base = (size_t)wi * NTOK * QKV_OUT + h * 96;
  for (int i = tid; i < NTOK * KD; i += 256) {
    int n = i >> 5, d = i & 31;
    const unsigned short* p = qkv + base + (size_t)n * QKV_OUT + d;
    q[n][d] = bf2f(p[0]) * SCALE;
    k[n][d] = bf2f(p[32]);
    v[n][d] = bf2f(p[64]);
  }
  if (tid < NTOK) bia[tid] = bf2f(attn_bias[h * NTOK + tid]);
  __syncthreads();
  for (int i = tid; i < NTOK * NTOK; i += 256) {
    int n = i / 49, m = i - n * 49;
    float s = 0.f;
    #pragma unroll
    for (int d = 0; d < KD; ++d) s += q[n][d] * k[m][d];
    S[n][m] = s + bia[bias_idxs[i]];
  }
  __syncthreads();
  const int lane = tid & 63, wv = tid >> 6;
  for (int n = wv; n < NTOK; n += 4) {
    float val = (lane < NTOK) ? S[n][lane] : -1e30f;
    for (int off = 32; off; off >>= 1) val = fmaxf(val, __shfl_xor(val, off));
    float e = (lane < NTOK) ? expf(S[n][lane] - val) : 0.f;
    float sum = e;
    for (int off = 32; off; off >>= 1) sum += __shfl_xor(sum, off);
    if (lane < NTOK) S[n][lane] = e / sum;
  }
  __syncthreads();
  for (int i = tid; i < NTOK * KD; i += 256) {
    int n = i >> 5, d = i & 31;
    float acc = 0.f;
    #pragma unroll 7
    for (int m = 0; m < NTOK; ++m) acc += S[n][m] * v[m][d];
    o[((size_t)(wi_off + wi) * NTOK + n) * CC + h * KD + d] = f2bf(acc);
  }
}

// ---------- depthwise 3x3 conv + BN ----------
__global__ __launch_bounds__(384) void conv_bn_kernel(
    const unsigned short* __restrict__ x1, const unsigned short* __restrict__ cw,
    const unsigned short* __restrict__ bg, const unsigned short* __restrict__ bb,
    const unsigned short* __restrict__ bm, const unsigned short* __restrict__ bv,
    unsigned short* __restrict__ x2) {
  const int hw = blockIdx.x;
  const int b = blockIdx.y;
  const int c = threadIdx.x;
  const int h = hw / 28, w = hw - h * 28;
  float wt[9];
  #pragma unroll
  for (int t = 0; t < 9; ++t) wt[t] = bf2f(cw[c * 9 + t]);
  float acc = 0.f;
  #pragma unroll
  for (int dh = -1; dh <= 1; ++dh) {
    int hh = h + dh;
    if (hh < 0 || hh >= 28) continue;
    #pragma unroll
    for (int dw = -1; dw <= 1; ++dw) {
      int ww = w + dw;
      if (ww < 0 || ww >= 28) continue;
      acc += bf2f(x1[((size_t)b * LL + hh * 28 + ww) * CC + c]) * wt[(dh + 1) * 3 + (dw + 1)];
    }
  }
  float inv = rsqrtf(bf2f(bv[c]) + EPS);
  float y = (acc - bf2f(bm[c])) * (bf2f(bg[c]) * inv) + bf2f(bb[c]);
  x2[((size_t)b * LL + hw) * CC + c] = f2bf(y);
}

// ---------- launch ----------
extern "C" void kernel_launch(void* const* d_in, const int* in_sizes, int n_in,
                              void* d_out, int out_size, void* d_ws, size_t ws_size,
                              hipStream_t stream) {
  int* flag = (int*)d_ws;
  unsigned short* base = (unsigned short*)d_ws;

  CvtArgs args;
  size_t cur = 32;
  size_t off[19];
  for (int i = 0; i < 19; ++i) {
    off[i] = cur;
    args.src[i] = d_in[i];
    args.n[i] = (unsigned int)in_sizes[i];
    args.off[i] = (unsigned int)cur;
    cur += ((size_t)in_sizes[i] + 63) & ~(size_t)63;
  }
  const unsigned short* cx   = base + off[0];
  const unsigned short* cgA  = base + off[1];
  const unsigned short* cbA  = base + off[2];
  const unsigned short* cQw  = base + off[3];
  const unsigned short* cQb  = base + off[4];
  const unsigned short* cAb  = base + off[5];
  const unsigned short* cPw  = base + off[6];
  const unsigned short* cPb  = base + off[7];
  const unsigned short* cCw  = base + off[8];
  const unsigned short* cBg  = base + off[9];
  const unsigned short* cBb  = base + off[10];
  const unsigned short* cBm  = base + off[11];
  const unsigned short* cBv  = base + off[12];
  const unsigned short* cMg  = base + off[13];
  const unsigned short* cMb  = base + off[14];
  const unsigned short* cF1w = base + off[15];
  const unsigned short* cF1b = base + off[16];
  const unsigned short* cF2w = base + off[17];
  const unsigned short* cF2b = base + off[18];
  const int* bias_idxs = (const int*)d_in[19];

  // working buffers (internal bf16), region-reused:
  const size_t SZ = (size_t)MTOT * CC;          // 19267584 elems
  unsigned short* o_buf = base + cur;            // attn out o; later xm (LN_m out)
  unsigned short* buf2  = o_buf + SZ;            // qkv half (attn phase) / h half (MLP phase)
  unsigned short* x2    = base + off[0];         // conv+BN out overwrites spent cx region
  // peak = cur + SZ + MTOT/2*HID elems (~158 MB, same as round 2)

  unsigned short* xn = (unsigned short*)d_out;   // d_out doubles as xn / x1 scratch

  // 0. dtype detect + canonicalize
  detect_kernel<<<1, 256, 0, stream>>>((const unsigned short*)d_in[0], flag);
  convert_kernel<<<dim3(1176, 19), 256, 0, stream>>>(args, base, flag);

  // 1. window partition + LN_a -> xn (d_out)
  ln_kernel<true><<<dim3(49, 1024), 128, 0, stream>>>(cx, cgA, cbA, xn);

  // 2+3. qkv projection + attention, 2 window-halves (M_half = 25088)
  for (int half = 0; half < 2; ++half) {
    gemm128<EP_PLAIN><<<dim3(196, 9), 256, 0, stream>>>(
        xn + (size_t)half * 25088 * CC, cQw, cQb, nullptr, buf2, CC, QKV_OUT, 0, nullptr);
    attn_kernel<<<dim3(512, NHEAD), 256, 0, stream>>>(buf2, cAb, bias_idxs, o_buf, half * 512);
  }

  // 4. proj + un-window + residual(x) -> x1 (d_out)
  gemm128<EP_WINRES><<<dim3(392, 3), 256, 0, stream>>>(
      o_buf, cPw, cPb, cx, d_out, CC, CC, 0, nullptr);

  // 5. depthwise conv + BN -> x2 (overwrites cx, which is now spent)
  conv_bn_kernel<<<dim3(784, BATCH), 384, 0, stream>>>(
      (const unsigned short*)d_out, cCw, cBg, cBb, cBm, cBv, x2);

  // 6. LN_m -> xm (o_buf)
  ln_kernel<false><<<dim3(49, 1024), 128, 0, stream>>>(x2, cMg, cMb, o_buf);

  // 7+8. MLP in 2 M-halves; fc2 writes final output (bf16 or f32 per flag)
  for (int half = 0; half < 2; ++half) {
    gemm128<EP_GELU><<<dim3(196, 12), 256, 0, stream>>>(
        o_buf + (size_t)half * 25088 * CC, cF1w, cF1b, nullptr, buf2, CC, HID, 0, nullptr);
    gemm128<EP_RES2><<<dim3(196, 3), 256, 0, stream>>>(
        buf2, cF2w, cF2b, x2, d_out, HID, CC, half * 25088, flag);
  }
}

// Round 4
// 928.312 us; speedup vs baseline: 1.4258x; 1.2177x over previous
//
#include <hip/hip_runtime.h>
#include <hip/hip_bf16.h>
#include <stdint.h>

// ---------- constants ----------
#define BATCH 64
#define CC 384
#define NHEAD 12
#define KD 32
#define NTOK 49
#define LL 784
#define MTOT 50176        // BATCH*LL = 1024 windows * 49
#define HID 1536
#define QKV_OUT 1152
#define SCALE 0.17677669529663687f
#define EPS 1e-5f

typedef __bf16 bf16x8 __attribute__((ext_vector_type(8)));
typedef float f32x4 __attribute__((ext_vector_type(4)));

__device__ __forceinline__ float bf2f(unsigned short u) {
  union { unsigned int u; float f; } cv; cv.u = ((unsigned int)u) << 16; return cv.f;
}
__device__ __forceinline__ unsigned short f2bf(float f) {
  union { float f; unsigned int u; } cv; cv.f = f;
  unsigned int r = cv.u + 0x7FFFu + ((cv.u >> 16) & 1u);
  return (unsigned short)(r >> 16);
}
__device__ __forceinline__ void gl_lds16(const unsigned short* g, unsigned short* l) {
  __builtin_amdgcn_global_load_lds(
      (const __attribute__((address_space(1))) unsigned int*)g,
      (__attribute__((address_space(3))) unsigned int*)l, 16, 0, 0);
}

// ---------- dtype detection (bf16 vs fp32 wire format) ----------
__global__ void detect_kernel(const unsigned short* __restrict__ x, int* flag) {
  __shared__ int cnt;
  if (threadIdx.x == 0) cnt = 0;
  __syncthreads();
  int c = 0;
  for (int i = threadIdx.x; i < 4096; i += 256) {
    if (((x[i] >> 7) & 0xFF) == 0xFF) c++;
  }
  atomicAdd(&cnt, c);
  __syncthreads();
  if (threadIdx.x == 0) *flag = (cnt > 0) ? 1 : 0;
}

// ---------- input canonicalization ----------
struct CvtArgs {
  const void* src[19];
  unsigned int n[19];
  unsigned int off[19];
};
__global__ __launch_bounds__(256) void convert_kernel(
    CvtArgs a, unsigned short* __restrict__ dst, const int* __restrict__ flag) {
  const int which = blockIdx.y;
  const unsigned int nn = a.n[which];
  unsigned short* d = dst + a.off[which];
  const unsigned int stride = gridDim.x * blockDim.x;
  unsigned int i = blockIdx.x * blockDim.x + threadIdx.x;
  if (*flag) {
    const float* s = (const float*)a.src[which];
    for (; i < nn; i += stride) d[i] = f2bf(s[i]);
  } else {
    const unsigned short* s = (const unsigned short*)a.src[which];
    for (; i < nn; i += stride) d[i] = s[i];
  }
}

// ---------- bias table precompute: bias_full[h][n][m] fp32 ----------
__global__ __launch_bounds__(256) void bias_kernel(
    const unsigned short* __restrict__ cAb, const int* __restrict__ bias_idxs,
    float* __restrict__ bias_full) {
  const int h = blockIdx.x;
  for (int i = threadIdx.x; i < NTOK * NTOK; i += 256)
    bias_full[h * NTOK * NTOK + i] = bf2f(cAb[h * NTOK + bias_idxs[i]]);
}

// ---------- LayerNorm (+ optional window gather) ----------
template <bool WINDOW>
__global__ __launch_bounds__(128) void ln_kernel(
    const unsigned short* __restrict__ x, const unsigned short* __restrict__ g,
    const unsigned short* __restrict__ b, unsigned short* __restrict__ out) {
  const int tid = threadIdx.x;
  size_t src_row, dst_row;
  if (WINDOW) {
    int wi = blockIdx.y, n = blockIdx.x;
    int bb = wi >> 4, wb = wi & 15;
    int nh_i = wb >> 2, nw_i = wb & 3;
    int hs = n / 7, wsx = n - hs * 7;
    int l = nh_i * 196 + hs * 28 + nw_i * 7 + wsx;
    src_row = (size_t)bb * LL + l;
    dst_row = (size_t)wi * NTOK + n;
  } else {
    src_row = dst_row = (size_t)blockIdx.y * 49 + blockIdx.x;
  }
  const unsigned short* xr = x + src_row * CC;
  float vals[3]; float s = 0.f, sq = 0.f;
  for (int j = 0; j < 3; ++j) {
    vals[j] = bf2f(xr[tid + 128 * j]);
    s += vals[j]; sq += vals[j] * vals[j];
  }
  for (int off = 32; off; off >>= 1) { s += __shfl_xor(s, off); sq += __shfl_xor(sq, off); }
  __shared__ float red[4];
  const int wv = tid >> 6;
  if ((tid & 63) == 0) { red[wv] = s; red[2 + wv] = sq; }
  __syncthreads();
  float tot = red[0] + red[1], totq = red[2] + red[3];
  float mean = tot * (1.f / CC);
  float var = totq * (1.f / CC) - mean * mean;
  float inv = rsqrtf(var + EPS);
  unsigned short* orow = out + dst_row * CC;
  for (int j = 0; j < 3; ++j) {
    int c = tid + 128 * j;
    float y = (vals[j] - mean) * inv * bf2f(g[c]) + bf2f(b[c]);
    orow[c] = f2bf(y);
  }
}

// ---------- GEMM (m97 recipe): 128x128 tile, 4 waves, 4x4 acc, async LDS ----------
enum { EP_PLAIN = 0, EP_GELU = 1, EP_WINRES = 2, EP_RES2 = 3 };

template <int EP>
__global__ __launch_bounds__(256) void gemm128(
    const unsigned short* __restrict__ A, const unsigned short* __restrict__ W,
    const unsigned short* __restrict__ bias, const unsigned short* __restrict__ res,
    void* __restrict__ outp, int K, int N, int m_off, const int* __restrict__ flagp) {
  __shared__ __align__(16) unsigned short Al[128 * 32];
  __shared__ __align__(16) unsigned short Bl[128 * 32];
  const int tid = threadIdx.x;
  const int lane = tid & 63;
  const int wave = tid >> 6;
  const int bm = blockIdx.x * 128;
  const int bn = blockIdx.y * 128;
  const int wm = (wave >> 1) * 64;
  const int wn = (wave & 1) * 64;
  const int srow = tid >> 2;
  const int scol = (tid & 3) * 8;
  const unsigned short* Ap = A + (size_t)(bm + srow) * K + scol;
  const unsigned short* Wp = W + (size_t)(bn + srow) * K + scol;
  unsigned short* Alp = Al + tid * 8;
  unsigned short* Blp = Bl + tid * 8;
  const size_t rstep = (size_t)64 * K;
  f32x4 acc[4][4] = {};
  const int kq = (lane >> 4) * 8;
  const int fr = lane & 15;
  for (int k0 = 0; k0 < K; k0 += 32) {
    __syncthreads();
    gl_lds16(Ap, Alp);
    gl_lds16(Ap + rstep, Alp + 2048);
    gl_lds16(Wp, Blp);
    gl_lds16(Wp + rstep, Blp + 2048);
    Ap += 32; Wp += 32;
    __syncthreads();
    bf16x8 af[4], bfr[4];
    #pragma unroll
    for (int i = 0; i < 4; ++i) {
      af[i]  = *(const bf16x8*)(Al + (wm + i * 16 + fr) * 32 + kq);
      bfr[i] = *(const bf16x8*)(Bl + (wn + i * 16 + fr) * 32 + kq);
    }
    #pragma unroll
    for (int i = 0; i < 4; ++i)
      #pragma unroll
      for (int j = 0; j < 4; ++j)
        acc[i][j] = __builtin_amdgcn_mfma_f32_16x16x32_bf16(af[i], bfr[j], acc[i][j], 0, 0, 0);
  }
  int isf32 = 0;
  if (EP == EP_RES2) isf32 = *flagp;
  const int qr = (lane >> 4) * 4;
  #pragma unroll
  for (int ti = 0; ti < 4; ++ti) {
    #pragma unroll
    for (int tj = 0; tj < 4; ++tj) {
      const int n = bn + wn + tj * 16 + fr;
      const float bv = bf2f(bias[n]);
      const int mbase = bm + wm + ti * 16 + qr;
      #pragma unroll
      for (int r = 0; r < 4; ++r) {
        const int mr = mbase + r;
        float v = acc[ti][tj][r] + bv;
        if (EP == EP_GELU) {
          v = 0.5f * v * (1.0f + erff(v * 0.70710678118654752f));
          ((unsigned short*)outp)[(size_t)mr * N + n] = f2bf(v);
        } else if (EP == EP_WINRES) {
          int wi = mr / 49; int nt = mr - wi * 49;
          int bb = wi >> 4; int wb = wi & 15;
          int nh_i = wb >> 2; int nw_i = wb & 3;
          int hs = nt / 7; int wsx = nt - hs * 7;
          int l = nh_i * 196 + hs * 28 + nw_i * 7 + wsx;
          size_t idx = ((size_t)bb * LL + l) * CC + n;
          v += bf2f(res[idx]);
          ((unsigned short*)outp)[idx] = f2bf(v);
        } else if (EP == EP_RES2) {
          size_t idx = (size_t)(mr + m_off) * N + n;
          v += bf2f(res[idx]);
          if (isf32) ((float*)outp)[idx] = v;
          else       ((unsigned short*)outp)[idx] = f2bf(v);
        } else {
          ((unsigned short*)outp)[(size_t)mr * N + n] = f2bf(v);
        }
      }
    }
  }
}

// ---------- MFMA windowed attention: one WAVE per (window, head) ----------
// QK^T: A=Q rows (token n), B=K rows (token m), both A-frag layout
// [row=lane&15][k=quad*8+j] loaded straight from global (16B/lane).
// C/D layout: row n = quad*4+reg (+i*16), col m = lane&15 (+j*16)  [HW-verified
// by the passing gemm128]. Softmax over cols via 16-lane shfl. P->LDS bf16
// (stride 72: row advance = 36 banks %32 = 4 -> 2-way on b128, free). V->LDS
// transposed. PV: A=P (k=token m), B=V^T rows d. O scaled by 1/rowsum.
__global__ __launch_bounds__(64) void attn_mfma(
    const unsigned short* __restrict__ qkv, const float* __restrict__ bias_full,
    unsigned short* __restrict__ o, int wi_off) {
  __shared__ __align__(16) unsigned short Pl[64 * 72];
  __shared__ __align__(16) unsigned short vT[32 * 72];
  const int wi = blockIdx.x, h = blockIdx.y;
  const int lane = threadIdx.x;
  const int l15 = lane & 15;
  const int quad = lane >> 4;
  const unsigned short* base = qkv + (size_t)wi * NTOK * QKV_OUT + h * 96;

  // Q/K fragments direct from global; rows >= 49 zeroed
  bf16x8 qf[4], kf[4];
  #pragma unroll
  for (int i = 0; i < 4; ++i) {
    const int n = i * 16 + l15;
    if (n < NTOK) {
      const unsigned short* p = base + (size_t)n * QKV_OUT + quad * 8;
      qf[i] = *(const bf16x8*)(p);
      kf[i] = *(const bf16x8*)(p + 32);
    } else {
      qf[i] = (bf16x8)0; kf[i] = (bf16x8)0;
    }
  }

  // zero vT (cols 49..63 must be 0), then fill transposed V
  for (int idx = lane; idx < 32 * 72; idx += 64) vT[idx] = 0;
  __syncthreads();
  for (int idx = lane; idx < NTOK * KD; idx += 64) {
    const int m = idx >> 5, d = idx & 31;
    vT[d * 72 + m] = base[(size_t)m * QKV_OUT + 64 + d];
  }

  // QK^T
  f32x4 acc[4][4] = {};
  #pragma unroll
  for (int i = 0; i < 4; ++i)
    #pragma unroll
    for (int j = 0; j < 4; ++j)
      acc[i][j] = __builtin_amdgcn_mfma_f32_16x16x32_bf16(qf[i], kf[j], acc[i][j], 0, 0, 0);

  // scale + bias + masked softmax; write unnormalized P (bf16) to LDS
  const float* bh = bias_full + h * NTOK * NTOK;
  float rinv[4][4];
  #pragma unroll
  for (int i = 0; i < 4; ++i) {
    #pragma unroll
    for (int r = 0; r < 4; ++r) {
      const int n = i * 16 + quad * 4 + r;
      float sv[4];
      #pragma unroll
      for (int j = 0; j < 4; ++j) {
        const int m = j * 16 + l15;
        float s = acc[i][j][r] * SCALE;
        if (n < NTOK && m < NTOK) s += bh[n * NTOK + m];
        if (m >= NTOK) s = -1e30f;
        sv[j] = s;
      }
      float mx = fmaxf(fmaxf(sv[0], sv[1]), fmaxf(sv[2], sv[3]));
      #pragma unroll
      for (int t = 1; t < 16; t <<= 1) mx = fmaxf(mx, __shfl_xor(mx, t));
      float sum = 0.f;
      #pragma unroll
      for (int j = 0; j < 4; ++j) {
        const float p = __expf(sv[j] - mx);  // m>=49 -> 0
        sum += p;
        Pl[n * 72 + j * 16 + l15] = f2bf(p);
      }
      #pragma unroll
      for (int t = 1; t < 16; t <<= 1) sum += __shfl_xor(sum, t);
      rinv[i][r] = 1.f / sum;
    }
  }
  __syncthreads();

  // PV: O[n][d], K-dim = 64 tokens (zero-padded)
  f32x4 acc2[4][2] = {};
  #pragma unroll
  for (int kk = 0; kk < 2; ++kk) {
    bf16x8 pf[4], vf[2];
    #pragma unroll
    for (int i = 0; i < 4; ++i)
      pf[i] = *(const bf16x8*)(Pl + (i * 16 + l15) * 72 + kk * 32 + quad * 8);
    #pragma unroll
    for (int jd = 0; jd < 2; ++jd)
      vf[jd] = *(const bf16x8*)(vT + (jd * 16 + l15) * 72 + kk * 32 + quad * 8);
    #pragma unroll
    for (int i = 0; i < 4; ++i)
      #pragma unroll
      for (int jd = 0; jd < 2; ++jd)
        acc2[i][jd] = __builtin_amdgcn_mfma_f32_16x16x32_bf16(pf[i], vf[jd], acc2[i][jd], 0, 0, 0);
  }

  // epilogue: normalize and store
  #pragma unroll
  for (int i = 0; i < 4; ++i) {
    #pragma unroll
    for (int r = 0; r < 4; ++r) {
      const int n = i * 16 + quad * 4 + r;
      if (n < NTOK) {
        const float ri = rinv[i][r];
        #pragma unroll
        for (int jd = 0; jd < 2; ++jd) {
          const int d = jd * 16 + l15;
          o[((size_t)(wi_off + wi) * NTOK + n) * CC + h * KD + d] = f2bf(acc2[i][jd][r] * ri);
        }
      }
    }
  }
}

// ---------- depthwise 3x3 conv + BN ----------
__global__ __launch_bounds__(384) void conv_bn_kernel(
    const unsigned short* __restrict__ x1, const unsigned short* __restrict__ cw,
    const unsigned short* __restrict__ bg, const unsigned short* __restrict__ bb,
    const unsigned short* __restrict__ bm, const unsigned short* __restrict__ bv,
    unsigned short* __restrict__ x2) {
  const int hw = blockIdx.x;
  const int b = blockIdx.y;
  const int c = threadIdx.x;
  const int h = hw / 28, w = hw - h * 28;
  float wt[9];
  #pragma unroll
  for (int t = 0; t < 9; ++t) wt[t] = bf2f(cw[c * 9 + t]);
  float acc = 0.f;
  #pragma unroll
  for (int dh = -1; dh <= 1; ++dh) {
    int hh = h + dh;
    if (hh < 0 || hh >= 28) continue;
    #pragma unroll
    for (int dw = -1; dw <= 1; ++dw) {
      int ww = w + dw;
      if (ww < 0 || ww >= 28) continue;
      acc += bf2f(x1[((size_t)b * LL + hh * 28 + ww) * CC + c]) * wt[(dh + 1) * 3 + (dw + 1)];
    }
  }
  float inv = rsqrtf(bf2f(bv[c]) + EPS);
  float y = (acc - bf2f(bm[c])) * (bf2f(bg[c]) * inv) + bf2f(bb[c]);
  x2[((size_t)b * LL + hw) * CC + c] = f2bf(y);
}

// ---------- launch ----------
extern "C" void kernel_launch(void* const* d_in, const int* in_sizes, int n_in,
                              void* d_out, int out_size, void* d_ws, size_t ws_size,
                              hipStream_t stream) {
  int* flag = (int*)d_ws;
  unsigned short* base = (unsigned short*)d_ws;

  CvtArgs args;
  size_t cur = 32;
  size_t off[19];
  for (int i = 0; i < 19; ++i) {
    off[i] = cur;
    args.src[i] = d_in[i];
    args.n[i] = (unsigned int)in_sizes[i];
    args.off[i] = (unsigned int)cur;
    cur += ((size_t)in_sizes[i] + 63) & ~(size_t)63;
  }
  const unsigned short* cx   = base + off[0];
  const unsigned short* cgA  = base + off[1];
  const unsigned short* cbA  = base + off[2];
  const unsigned short* cQw  = base + off[3];
  const unsigned short* cQb  = base + off[4];
  const unsigned short* cAb  = base + off[5];
  const unsigned short* cPw  = base + off[6];
  const unsigned short* cPb  = base + off[7];
  const unsigned short* cCw  = base + off[8];
  const unsigned short* cBg  = base + off[9];
  const unsigned short* cBb  = base + off[10];
  const unsigned short* cBm  = base + off[11];
  const unsigned short* cBv  = base + off[12];
  const unsigned short* cMg  = base + off[13];
  const unsigned short* cMb  = base + off[14];
  const unsigned short* cF1w = base + off[15];
  const unsigned short* cF1b = base + off[16];
  const unsigned short* cF2w = base + off[17];
  const unsigned short* cF2b = base + off[18];
  const int* bias_idxs = (const int*)d_in[19];

  const size_t SZ = (size_t)MTOT * CC;             // 19267584 elems
  unsigned short* o_buf = base + cur;               // attn out o; later xm
  unsigned short* buf2  = o_buf + SZ;               // qkv half / h half
  unsigned short* x2    = base + off[0];            // conv+BN out overwrites spent cx
  float* bias_full = (float*)(buf2 + (size_t)25088 * HID);  // [12][49][49] fp32

  unsigned short* xn = (unsigned short*)d_out;

  // 0. dtype detect + canonicalize + bias table
  detect_kernel<<<1, 256, 0, stream>>>((const unsigned short*)d_in[0], flag);
  convert_kernel<<<dim3(1176, 19), 256, 0, stream>>>(args, base, flag);
  bias_kernel<<<NHEAD, 256, 0, stream>>>(cAb, bias_idxs, bias_full);

  // 1. window partition + LN_a -> xn (d_out)
  ln_kernel<true><<<dim3(49, 1024), 128, 0, stream>>>(cx, cgA, cbA, xn);

  // 2+3. qkv projection + MFMA attention, 2 window-halves
  for (int half = 0; half < 2; ++half) {
    gemm128<EP_PLAIN><<<dim3(196, 9), 256, 0, stream>>>(
        xn + (size_t)half * 25088 * CC, cQw, cQb, nullptr, buf2, CC, QKV_OUT, 0, nullptr);
    attn_mfma<<<dim3(512, NHEAD), 64, 0, stream>>>(buf2, bias_full, o_buf, half * 512);
  }

  // 4. proj + un-window + residual(x) -> x1 (d_out)
  gemm128<EP_WINRES><<<dim3(392, 3), 256, 0, stream>>>(
      o_buf, cPw, cPb, cx, d_out, CC, CC, 0, nullptr);

  // 5. depthwise conv + BN -> x2
  conv_bn_kernel<<<dim3(784, BATCH), 384, 0, stream>>>(
      (const unsigned short*)d_out, cCw, cBg, cBb, cBm, cBv, x2);

  // 6. LN_m -> xm (o_buf)
  ln_kernel<false><<<dim3(49, 1024), 128, 0, stream>>>(x2, cMg, cMb, o_buf);

  // 7+8. MLP in 2 M-halves; fc2 writes final output
  for (int half = 0; half < 2; ++half) {
    gemm128<EP_GELU><<<dim3(196, 12), 256, 0, stream>>>(
        o_buf + (size_t)half * 25088 * CC, cF1w, cF1b, nullptr, buf2, CC, HID, 0, nullptr);
    gemm128<EP_RES2><<<dim3(196, 3), 256, 0, stream>>>(
        buf2, cF2w, cF2b, x2, d_out, HID, CC, half * 25088, flag);
  }
}

// Round 5
// 787.512 us; speedup vs baseline: 1.6808x; 1.1788x over previous
//
#include <hip/hip_runtime.h>
#include <hip/hip_bf16.h>
#include <stdint.h>

// ---------- constants ----------
#define BATCH 64
#define CC 384
#define NHEAD 12
#define KD 32
#define NTOK 49
#define LL 784
#define MTOT 50176        // BATCH*LL = 1024 windows * 49
#define HID 1536
#define QKV_OUT 1152
#define SCALE 0.17677669529663687f
#define EPS 1e-5f

typedef __bf16 bf16x8 __attribute__((ext_vector_type(8)));
typedef float f32x4 __attribute__((ext_vector_type(4)));

__device__ __forceinline__ float bf2f(unsigned short u) {
  union { unsigned int u; float f; } cv; cv.u = ((unsigned int)u) << 16; return cv.f;
}
__device__ __forceinline__ unsigned short f2bf(float f) {
  union { float f; unsigned int u; } cv; cv.f = f;
  unsigned int r = cv.u + 0x7FFFu + ((cv.u >> 16) & 1u);
  return (unsigned short)(r >> 16);
}
__device__ __forceinline__ void gl_lds16(const unsigned short* g, unsigned short* l) {
  __builtin_amdgcn_global_load_lds(
      (const __attribute__((address_space(1))) unsigned int*)g,
      (__attribute__((address_space(3))) unsigned int*)l, 16, 0, 0);
}

// ---------- dtype detection (bf16 vs fp32 wire format) ----------
__global__ void detect_kernel(const unsigned short* __restrict__ x, int* flag) {
  __shared__ int cnt;
  if (threadIdx.x == 0) cnt = 0;
  __syncthreads();
  int c = 0;
  for (int i = threadIdx.x; i < 4096; i += 256) {
    if (((x[i] >> 7) & 0xFF) == 0xFF) c++;
  }
  atomicAdd(&cnt, c);
  __syncthreads();
  if (threadIdx.x == 0) *flag = (cnt > 0) ? 1 : 0;
}

// ---------- input canonicalization (vectorized) ----------
struct CvtArgs {
  const void* src[19];
  unsigned int n[19];
  unsigned int off[19];
};
__global__ __launch_bounds__(256) void convert_kernel(
    CvtArgs a, unsigned short* __restrict__ dst, const int* __restrict__ flag) {
  const int which = blockIdx.y;
  const unsigned int nn = a.n[which];
  unsigned short* d = dst + a.off[which];
  const unsigned int stride = gridDim.x * blockDim.x;
  const unsigned int idx = blockIdx.x * blockDim.x + threadIdx.x;
  const unsigned int ng = nn >> 3;
  if (*flag) {
    const float* s = (const float*)a.src[which];
    for (unsigned int g = idx; g < ng; g += stride) {
      const float4 f0 = ((const float4*)s)[g * 2];
      const float4 f1 = ((const float4*)s)[g * 2 + 1];
      ushort4 lo, hi;
      lo.x = f2bf(f0.x); lo.y = f2bf(f0.y); lo.z = f2bf(f0.z); lo.w = f2bf(f0.w);
      hi.x = f2bf(f1.x); hi.y = f2bf(f1.y); hi.z = f2bf(f1.z); hi.w = f2bf(f1.w);
      ((ushort4*)d)[g * 2] = lo;
      ((ushort4*)d)[g * 2 + 1] = hi;
    }
    for (unsigned int i = ng * 8 + idx; i < nn; i += stride) d[i] = f2bf(s[i]);
  } else {
    const unsigned short* s = (const unsigned short*)a.src[which];
    for (unsigned int g = idx; g < ng; g += stride)
      ((uint4*)d)[g] = ((const uint4*)s)[g];
    for (unsigned int i = ng * 8 + idx; i < nn; i += stride) d[i] = s[i];
  }
}

// ---------- bias table precompute: bias_full[h][n][m] fp32 ----------
__global__ __launch_bounds__(256) void bias_kernel(
    const unsigned short* __restrict__ cAb, const int* __restrict__ bias_idxs,
    float* __restrict__ bias_full) {
  const int h = blockIdx.x;
  for (int i = threadIdx.x; i < NTOK * NTOK; i += 256)
    bias_full[h * NTOK * NTOK + i] = bf2f(cAb[h * NTOK + bias_idxs[i]]);
}

// ---------- conv/BN table precompute: cwT[t][c] bf16, bn scale/shift fp32 ----------
__global__ __launch_bounds__(384) void prep_kernel(
    const unsigned short* __restrict__ cw, const unsigned short* __restrict__ bg,
    const unsigned short* __restrict__ bb, const unsigned short* __restrict__ bm,
    const unsigned short* __restrict__ bv,
    unsigned short* __restrict__ cwT, float* __restrict__ bnsc, float* __restrict__ bnsh) {
  const int c = threadIdx.x;
  const float sc = bf2f(bg[c]) * rsqrtf(bf2f(bv[c]) + EPS);
  bnsc[c] = sc;
  bnsh[c] = bf2f(bb[c]) - bf2f(bm[c]) * sc;
  #pragma unroll
  for (int t = 0; t < 9; ++t) cwT[t * CC + c] = cw[c * 9 + t];
}

// ---------- LayerNorm + window gather (pre-attention) ----------
__global__ __launch_bounds__(128) void ln_kernel(
    const unsigned short* __restrict__ x, const unsigned short* __restrict__ g,
    const unsigned short* __restrict__ b, unsigned short* __restrict__ out) {
  const int tid = threadIdx.x;
  int wi = blockIdx.y, n = blockIdx.x;
  int bb = wi >> 4, wb = wi & 15;
  int nh_i = wb >> 2, nw_i = wb & 3;
  int hs = n / 7, wsx = n - hs * 7;
  int l = nh_i * 196 + hs * 28 + nw_i * 7 + wsx;
  size_t src_row = (size_t)bb * LL + l;
  size_t dst_row = (size_t)wi * NTOK + n;
  const unsigned short* xr = x + src_row * CC;
  float vals[3]; float s = 0.f, sq = 0.f;
  for (int j = 0; j < 3; ++j) {
    vals[j] = bf2f(xr[tid + 128 * j]);
    s += vals[j]; sq += vals[j] * vals[j];
  }
  for (int off = 32; off; off >>= 1) { s += __shfl_xor(s, off); sq += __shfl_xor(sq, off); }
  __shared__ float red[4];
  const int wv = tid >> 6;
  if ((tid & 63) == 0) { red[wv] = s; red[2 + wv] = sq; }
  __syncthreads();
  float tot = red[0] + red[1], totq = red[2] + red[3];
  float mean = tot * (1.f / CC);
  float var = totq * (1.f / CC) - mean * mean;
  float inv = rsqrtf(var + EPS);
  unsigned short* orow = out + dst_row * CC;
  for (int j = 0; j < 3; ++j) {
    int c = tid + 128 * j;
    float y = (vals[j] - mean) * inv * bf2f(g[c]) + bf2f(b[c]);
    orow[c] = f2bf(y);
  }
}

// ---------- GEMM (m97 recipe): 128x128 tile, 4 waves, 4x4 acc, async LDS ----------
enum { EP_PLAIN = 0, EP_GELU = 1, EP_WINRES = 2, EP_RES2 = 3 };

template <int EP>
__global__ __launch_bounds__(256) void gemm128(
    const unsigned short* __restrict__ A, const unsigned short* __restrict__ W,
    const unsigned short* __restrict__ bias, const unsigned short* __restrict__ res,
    void* __restrict__ outp, int K, int N, int m_off, const int* __restrict__ flagp) {
  __shared__ __align__(16) unsigned short Al[128 * 32];
  __shared__ __align__(16) unsigned short Bl[128 * 32];
  const int tid = threadIdx.x;
  const int lane = tid & 63;
  const int wave = tid >> 6;
  const int bm = blockIdx.x * 128;
  const int bn = blockIdx.y * 128;
  const int wm = (wave >> 1) * 64;
  const int wn = (wave & 1) * 64;
  const int srow = tid >> 2;
  const int scol = (tid & 3) * 8;
  const unsigned short* Ap = A + (size_t)(bm + srow) * K + scol;
  const unsigned short* Wp = W + (size_t)(bn + srow) * K + scol;
  unsigned short* Alp = Al + tid * 8;
  unsigned short* Blp = Bl + tid * 8;
  const size_t rstep = (size_t)64 * K;
  f32x4 acc[4][4] = {};
  const int kq = (lane >> 4) * 8;
  const int fr = lane & 15;
  for (int k0 = 0; k0 < K; k0 += 32) {
    __syncthreads();
    gl_lds16(Ap, Alp);
    gl_lds16(Ap + rstep, Alp + 2048);
    gl_lds16(Wp, Blp);
    gl_lds16(Wp + rstep, Blp + 2048);
    Ap += 32; Wp += 32;
    __syncthreads();
    bf16x8 af[4], bfr[4];
    #pragma unroll
    for (int i = 0; i < 4; ++i) {
      af[i]  = *(const bf16x8*)(Al + (wm + i * 16 + fr) * 32 + kq);
      bfr[i] = *(const bf16x8*)(Bl + (wn + i * 16 + fr) * 32 + kq);
    }
    #pragma unroll
    for (int i = 0; i < 4; ++i)
      #pragma unroll
      for (int j = 0; j < 4; ++j)
        acc[i][j] = __builtin_amdgcn_mfma_f32_16x16x32_bf16(af[i], bfr[j], acc[i][j], 0, 0, 0);
  }
  int isf32 = 0;
  if (EP == EP_RES2) isf32 = *flagp;
  const int qr = (lane >> 4) * 4;
  #pragma unroll
  for (int ti = 0; ti < 4; ++ti) {
    #pragma unroll
    for (int tj = 0; tj < 4; ++tj) {
      const int n = bn + wn + tj * 16 + fr;
      const float bv = bf2f(bias[n]);
      const int mbase = bm + wm + ti * 16 + qr;
      #pragma unroll
      for (int r = 0; r < 4; ++r) {
        const int mr = mbase + r;
        float v = acc[ti][tj][r] + bv;
        if (EP == EP_GELU) {
          v = 0.5f * v * (1.0f + erff(v * 0.70710678118654752f));
          ((unsigned short*)outp)[(size_t)mr * N + n] = f2bf(v);
        } else if (EP == EP_WINRES) {
          int wi = mr / 49; int nt = mr - wi * 49;
          int bb = wi >> 4; int wb = wi & 15;
          int nh_i = wb >> 2; int nw_i = wb & 3;
          int hs = nt / 7; int wsx = nt - hs * 7;
          int l = nh_i * 196 + hs * 28 + nw_i * 7 + wsx;
          size_t idx = ((size_t)bb * LL + l) * CC + n;
          v += bf2f(res[idx]);
          ((unsigned short*)outp)[idx] = f2bf(v);
        } else if (EP == EP_RES2) {
          size_t idx = (size_t)(mr + m_off) * N + n;
          v += bf2f(res[idx]);
          if (isf32) ((float*)outp)[idx] = v;
          else       ((unsigned short*)outp)[idx] = f2bf(v);
        } else {
          ((unsigned short*)outp)[(size_t)mr * N + n] = f2bf(v);
        }
      }
    }
  }
}

// ---------- MFMA windowed attention: one WAVE per (window, head) ----------
__global__ __launch_bounds__(64) void attn_mfma(
    const unsigned short* __restrict__ qkv, const float* __restrict__ bias_full,
    unsigned short* __restrict__ o, int wi_off) {
  __shared__ __align__(16) unsigned short Pl[64 * 72];
  __shared__ __align__(16) unsigned short vT[32 * 72];
  const int wi = blockIdx.x, h = blockIdx.y;
  const int lane = threadIdx.x;
  const int l15 = lane & 15;
  const int quad = lane >> 4;
  const unsigned short* base = qkv + (size_t)wi * NTOK * QKV_OUT + h * 96;

  bf16x8 qf[4], kf[4];
  #pragma unroll
  for (int i = 0; i < 4; ++i) {
    const int n = i * 16 + l15;
    if (n < NTOK) {
      const unsigned short* p = base + (size_t)n * QKV_OUT + quad * 8;
      qf[i] = *(const bf16x8*)(p);
      kf[i] = *(const bf16x8*)(p + 32);
    } else {
      qf[i] = (bf16x8)0; kf[i] = (bf16x8)0;
    }
  }

  for (int idx = lane; idx < 32 * 72; idx += 64) vT[idx] = 0;
  __syncthreads();
  for (int idx = lane; idx < NTOK * KD; idx += 64) {
    const int m = idx >> 5, d = idx & 31;
    vT[d * 72 + m] = base[(size_t)m * QKV_OUT + 64 + d];
  }

  f32x4 acc[4][4] = {};
  #pragma unroll
  for (int i = 0; i < 4; ++i)
    #pragma unroll
    for (int j = 0; j < 4; ++j)
      acc[i][j] = __builtin_amdgcn_mfma_f32_16x16x32_bf16(qf[i], kf[j], acc[i][j], 0, 0, 0);

  const float* bh = bias_full + h * NTOK * NTOK;
  float rinv[4][4];
  #pragma unroll
  for (int i = 0; i < 4; ++i) {
    #pragma unroll
    for (int r = 0; r < 4; ++r) {
      const int n = i * 16 + quad * 4 + r;
      float sv[4];
      #pragma unroll
      for (int j = 0; j < 4; ++j) {
        const int m = j * 16 + l15;
        float s = acc[i][j][r] * SCALE;
        if (n < NTOK && m < NTOK) s += bh[n * NTOK + m];
        if (m >= NTOK) s = -1e30f;
        sv[j] = s;
      }
      float mx = fmaxf(fmaxf(sv[0], sv[1]), fmaxf(sv[2], sv[3]));
      #pragma unroll
      for (int t = 1; t < 16; t <<= 1) mx = fmaxf(mx, __shfl_xor(mx, t));
      float sum = 0.f;
      #pragma unroll
      for (int j = 0; j < 4; ++j) {
        const float p = __expf(sv[j] - mx);
        sum += p;
        Pl[n * 72 + j * 16 + l15] = f2bf(p);
      }
      #pragma unroll
      for (int t = 1; t < 16; t <<= 1) sum += __shfl_xor(sum, t);
      rinv[i][r] = 1.f / sum;
    }
  }
  __syncthreads();

  f32x4 acc2[4][2] = {};
  #pragma unroll
  for (int kk = 0; kk < 2; ++kk) {
    bf16x8 pf[4], vf[2];
    #pragma unroll
    for (int i = 0; i < 4; ++i)
      pf[i] = *(const bf16x8*)(Pl + (i * 16 + l15) * 72 + kk * 32 + quad * 8);
    #pragma unroll
    for (int jd = 0; jd < 2; ++jd)
      vf[jd] = *(const bf16x8*)(vT + (jd * 16 + l15) * 72 + kk * 32 + quad * 8);
    #pragma unroll
    for (int i = 0; i < 4; ++i)
      #pragma unroll
      for (int jd = 0; jd < 2; ++jd)
        acc2[i][jd] = __builtin_amdgcn_mfma_f32_16x16x32_bf16(pf[i], vf[jd], acc2[i][jd], 0, 0, 0);
  }

  #pragma unroll
  for (int i = 0; i < 4; ++i) {
    #pragma unroll
    for (int r = 0; r < 4; ++r) {
      const int n = i * 16 + quad * 4 + r;
      if (n < NTOK) {
        const float ri = rinv[i][r];
        #pragma unroll
        for (int jd = 0; jd < 2; ++jd) {
          const int d = jd * 16 + l15;
          o[((size_t)(wi_off + wi) * NTOK + n) * CC + h * KD + d] = f2bf(acc2[i][jd][r] * ri);
        }
      }
    }
  }
}

// ---------- fused depthwise 3x3 conv + BN + LN_m ----------
// grid (98, 64), block 384. Thread = (pos 0..7, c8 0..47): 8 channels via uint4.
// Writes x2 (conv+BN, for fc2 residual) AND xm (LayerNorm'd, for fc1 input).
__global__ __launch_bounds__(384) void conv_bn_ln(
    const unsigned short* __restrict__ x1, const unsigned short* __restrict__ cwT,
    const float* __restrict__ bnsc, const float* __restrict__ bnsh,
    const unsigned short* __restrict__ mg, const unsigned short* __restrict__ mb,
    unsigned short* __restrict__ x2, unsigned short* __restrict__ xm) {
  __shared__ float rs[8][48], rq[8][48];
  const int tid = threadIdx.x;
  const int pos = tid / 48;
  const int c8 = tid - pos * 48;
  const int c0 = c8 * 8;
  const int hw = blockIdx.x * 8 + pos;
  const int b = blockIdx.y;
  const int h = hw / 28, w = hw - h * 28;
  float acc[8] = {};
  #pragma unroll
  for (int t = 0; t < 9; ++t) {
    const int dh = t / 3 - 1, dw = t % 3 - 1;
    const int hh = h + dh, ww = w + dw;
    if (hh >= 0 && hh < 28 && ww >= 0 && ww < 28) {
      const uint4 xv = *(const uint4*)(x1 + ((size_t)b * LL + hh * 28 + ww) * CC + c0);
      const uint4 wv = *(const uint4*)(cwT + t * CC + c0);
      const unsigned short* xp = (const unsigned short*)&xv;
      const unsigned short* wp = (const unsigned short*)&wv;
      #pragma unroll
      for (int k = 0; k < 8; ++k) acc[k] += bf2f(xp[k]) * bf2f(wp[k]);
    }
  }
  const float4 sc0 = *(const float4*)(bnsc + c0);
  const float4 sc1 = *(const float4*)(bnsc + c0 + 4);
  const float4 sh0 = *(const float4*)(bnsh + c0);
  const float4 sh1 = *(const float4*)(bnsh + c0 + 4);
  float y[8];
  y[0] = acc[0] * sc0.x + sh0.x; y[1] = acc[1] * sc0.y + sh0.y;
  y[2] = acc[2] * sc0.z + sh0.z; y[3] = acc[3] * sc0.w + sh0.w;
  y[4] = acc[4] * sc1.x + sh1.x; y[5] = acc[5] * sc1.y + sh1.y;
  y[6] = acc[6] * sc1.z + sh1.z; y[7] = acc[7] * sc1.w + sh1.w;
  ushort4 pk0, pk1;
  pk0.x = f2bf(y[0]); pk0.y = f2bf(y[1]); pk0.z = f2bf(y[2]); pk0.w = f2bf(y[3]);
  pk1.x = f2bf(y[4]); pk1.y = f2bf(y[5]); pk1.z = f2bf(y[6]); pk1.w = f2bf(y[7]);
  const size_t row = ((size_t)b * LL + hw) * CC + c0;
  *(ushort4*)(x2 + row) = pk0;
  *(ushort4*)(x2 + row + 4) = pk1;
  // LN reduction across the row (48 threads share pos)
  float s = 0.f, q = 0.f;
  #pragma unroll
  for (int k = 0; k < 8; ++k) { s += y[k]; q += y[k] * y[k]; }
  rs[pos][c8] = s; rq[pos][c8] = q;
  __syncthreads();
  float tot = 0.f, tq = 0.f;
  #pragma unroll 8
  for (int i = 0; i < 48; ++i) { tot += rs[pos][i]; tq += rq[pos][i]; }
  const float mean = tot * (1.f / CC);
  const float var = tq * (1.f / CC) - mean * mean;
  const float inv = rsqrtf(var + EPS);
  const uint4 gv = *(const uint4*)(mg + c0);
  const uint4 bv = *(const uint4*)(mb + c0);
  const unsigned short* gp = (const unsigned short*)&gv;
  const unsigned short* bp = (const unsigned short*)&bv;
  ushort4 lo, hi;
  unsigned short outv[8];
  #pragma unroll
  for (int k = 0; k < 8; ++k)
    outv[k] = f2bf((y[k] - mean) * inv * bf2f(gp[k]) + bf2f(bp[k]));
  lo.x = outv[0]; lo.y = outv[1]; lo.z = outv[2]; lo.w = outv[3];
  hi.x = outv[4]; hi.y = outv[5]; hi.z = outv[6]; hi.w = outv[7];
  *(ushort4*)(xm + row) = lo;
  *(ushort4*)(xm + row + 4) = hi;
}

// ---------- launch ----------
extern "C" void kernel_launch(void* const* d_in, const int* in_sizes, int n_in,
                              void* d_out, int out_size, void* d_ws, size_t ws_size,
                              hipStream_t stream) {
  int* flag = (int*)d_ws;
  unsigned short* base = (unsigned short*)d_ws;

  CvtArgs args;
  size_t cur = 32;
  size_t off[19];
  for (int i = 0; i < 19; ++i) {
    off[i] = cur;
    args.src[i] = d_in[i];
    args.n[i] = (unsigned int)in_sizes[i];
    args.off[i] = (unsigned int)cur;
    cur += ((size_t)in_sizes[i] + 63) & ~(size_t)63;
  }
  const unsigned short* cx   = base + off[0];
  const unsigned short* cgA  = base + off[1];
  const unsigned short* cbA  = base + off[2];
  const unsigned short* cQw  = base + off[3];
  const unsigned short* cQb  = base + off[4];
  const unsigned short* cAb  = base + off[5];
  const unsigned short* cPw  = base + off[6];
  const unsigned short* cPb  = base + off[7];
  const unsigned short* cCw  = base + off[8];
  const unsigned short* cBg  = base + off[9];
  const unsigned short* cBb  = base + off[10];
  const unsigned short* cBm  = base + off[11];
  const unsigned short* cBv  = base + off[12];
  const unsigned short* cMg  = base + off[13];
  const unsigned short* cMb  = base + off[14];
  const unsigned short* cF1w = base + off[15];
  const unsigned short* cF1b = base + off[16];
  const unsigned short* cF2w = base + off[17];
  const unsigned short* cF2b = base + off[18];
  const int* bias_idxs = (const int*)d_in[19];

  const size_t SZ = (size_t)MTOT * CC;             // 19267584 elems
  unsigned short* o_buf = base + cur;               // attn out o; later xm
  unsigned short* buf2  = o_buf + SZ;               // qkv half / h half
  unsigned short* x2    = base + off[0];            // conv+BN out overwrites spent cx
  float* bias_full = (float*)(buf2 + (size_t)25088 * HID);      // [12][49][49] f32
  unsigned short* cwT = (unsigned short*)(bias_full + 12 * NTOK * NTOK);  // [9][384] bf16
  float* bnsc = (float*)(cwT + 9 * CC + ((9 * CC) & 7 ? 0 : 0)); // 3456 u16, 16B-ok
  float* bnsh = bnsc + CC;

  unsigned short* xn = (unsigned short*)d_out;

  // 0. dtype detect + canonicalize + tables
  detect_kernel<<<1, 256, 0, stream>>>((const unsigned short*)d_in[0], flag);
  convert_kernel<<<dim3(512, 19), 256, 0, stream>>>(args, base, flag);
  bias_kernel<<<NHEAD, 256, 0, stream>>>(cAb, bias_idxs, bias_full);
  prep_kernel<<<1, 384, 0, stream>>>(cCw, cBg, cBb, cBm, cBv, cwT, bnsc, bnsh);

  // 1. window partition + LN_a -> xn (d_out)
  ln_kernel<<<dim3(49, 1024), 128, 0, stream>>>(cx, cgA, cbA, xn);

  // 2+3. qkv projection + MFMA attention, 2 window-halves
  for (int half = 0; half < 2; ++half) {
    gemm128<EP_PLAIN><<<dim3(196, 9), 256, 0, stream>>>(
        xn + (size_t)half * 25088 * CC, cQw, cQb, nullptr, buf2, CC, QKV_OUT, 0, nullptr);
    attn_mfma<<<dim3(512, NHEAD), 64, 0, stream>>>(buf2, bias_full, o_buf, half * 512);
  }

  // 4. proj + un-window + residual(x) -> x1 (d_out)
  gemm128<EP_WINRES><<<dim3(392, 3), 256, 0, stream>>>(
      o_buf, cPw, cPb, cx, d_out, CC, CC, 0, nullptr);

  // 5. fused conv + BN + LN_m -> x2 (residual) and xm (o_buf, fc1 input)
  conv_bn_ln<<<dim3(98, BATCH), 384, 0, stream>>>(
      (const unsigned short*)d_out, cwT, bnsc, bnsh, cMg, cMb, x2, o_buf);

  // 6+7. MLP in 2 M-halves; fc2 writes final output
  for (int half = 0; half < 2; ++half) {
    gemm128<EP_GELU><<<dim3(196, 12), 256, 0, stream>>>(
        o_buf + (size_t)half * 25088 * CC, cF1w, cF1b, nullptr, buf2, CC, HID, 0, nullptr);
    gemm128<EP_RES2><<<dim3(196, 3), 256, 0, stream>>>(
        buf2, cF2w, cF2b, x2, d_out, HID, CC, half * 25088, flag);
  }
}